// Round 1
// baseline (3673.922 us; speedup 1.0000x reference)
//
#include <hip/hip_runtime.h>

// MySimpleRNN: h_t = tanh(x_t @ W_xh + h_{t-1} @ W_hh + b_h), return all h_t.
// B=64, T=1024, D=256, U=512, fp32 in/out.
//
// Kernel A: xw = X@W_xh + b  (fp32 VALU tiled GEMM) -> staged in d_out.
// Kernel B (round-3 restructure): 16 WGs of 512 threads = 4 groups (16 batches)
//   x 4 col-slices (128 cols). Wave w of 8 owns 16 cols with FULL K=512
//   (whi[16]+wlo[16] = 128 VGPRs of resident W_hh) -> no kh split, no red[]
//   exchange, each wave computes its own tanh. 3 peers instead of 15.
//   A (h_{t-1} bf16 hi/lo) double-buffered in LDS by t-parity -> ONE barrier
//   per step. Per-wave flags (8/WG) padded to 128B lines; each consumer wave
//   polls exactly 3 flags. Ring/flags remain RELAXED agent-scope atomics.
//   h fp32 HBM store delayed one step; xw prefetched one step ahead.

typedef __attribute__((ext_vector_type(8))) short short8;
typedef __attribute__((ext_vector_type(4))) float f32x4;

#define T_SZ 1024
#define U_SZ 512

typedef union { unsigned long long q[2]; short8 v; } chunk16;

__device__ __forceinline__ unsigned short f2bf(float f){
  unsigned u = __float_as_uint(f);
  u += 0x7FFFu + ((u >> 16) & 1u);           // round-to-nearest-even
  return (unsigned short)(u >> 16);
}
__device__ __forceinline__ float bf2f(unsigned short s){
  return __uint_as_float(((unsigned)s) << 16);
}

// ---------------- Kernel A: xw = X @ W_xh + b ----------------
// X: [65536,256] row-major, W: [256,512], out: [65536,512]
__global__ __launch_bounds__(256) void xw_gemm(const float* __restrict__ X,
                                               const float* __restrict__ W,
                                               const float* __restrict__ bias,
                                               float* __restrict__ out){
  __shared__ float As[16][132];   // [k][m], m-tile 128 (+4 pad)
  __shared__ float Bs[16][68];    // [k][n], n-tile 64  (+4 pad)
  const int tid = threadIdx.x;
  const int tx = tid & 15, ty = tid >> 4;
  const int row0 = blockIdx.x * 128;
  const int col0 = blockIdx.y * 64;
  float acc[8][4];
  #pragma unroll
  for(int a=0;a<8;a++)
    #pragma unroll
    for(int b=0;b<4;b++) acc[a][b]=0.f;

  for(int kc=0;kc<256;kc+=16){
    {
      const int m  = tid >> 2;
      const int kq = (tid & 3) * 4;
      #pragma unroll
      for(int h=0;h<2;h++){
        const float4 v = *(const float4*)&X[(size_t)(row0 + m + 64*h)*256 + kc + kq];
        As[kq+0][m+64*h]=v.x; As[kq+1][m+64*h]=v.y;
        As[kq+2][m+64*h]=v.z; As[kq+3][m+64*h]=v.w;
      }
    }
    {
      const int k = tid >> 4;
      const int c = (tid & 15) * 4;
      *(float4*)&Bs[k][c] = *(const float4*)&W[(size_t)(kc + k)*512 + col0 + c];
    }
    __syncthreads();
    #pragma unroll
    for(int k=0;k<16;k++){
      const float4 b4 = *(const float4*)&Bs[k][tx*4];
      const float4 a0 = *(const float4*)&As[k][ty*8];
      const float4 a1 = *(const float4*)&As[k][ty*8+4];
      const float av[8] = {a0.x,a0.y,a0.z,a0.w,a1.x,a1.y,a1.z,a1.w};
      const float bv[4] = {b4.x,b4.y,b4.z,b4.w};
      #pragma unroll
      for(int ii=0;ii<8;ii++)
        #pragma unroll
        for(int j=0;j<4;j++) acc[ii][j] = fmaf(av[ii], bv[j], acc[ii][j]);
    }
    __syncthreads();
  }
  #pragma unroll
  for(int ii=0;ii<8;ii++){
    const int row = row0 + ty*8 + ii;
    float4 o;
    o.x = acc[ii][0] + bias[col0+tx*4+0];
    o.y = acc[ii][1] + bias[col0+tx*4+1];
    o.z = acc[ii][2] + bias[col0+tx*4+2];
    o.w = acc[ii][3] + bias[col0+tx*4+3];
    *(float4*)&out[(size_t)row*512 + col0 + tx*4] = o;
  }
}

// ---------------- Kernel B: the recurrence ----------------
// grid 16, block 512 (8 waves). bid -> g = bid&3 (16-batch group),
// i = bid>>2 (128-col slice). Wave w: 16 cols ncol0 = i*128 + w*16, full K.
//
// Ring chunk (slot,g,p,w): 1KB = hi plane 512B (16 rows x 16 cols bf16,
// row-major, A-frag layout) + lo plane 512B. Lane l: sel=l>>5 (plane),
// m=(l&31)>>1 (row), q=l&1 (8-col half) -> 16B at ull off sel*64+m*4+q*2.
// Flags: flags[((g*4+i)*8+w)*32], value t+1 = "h_t published", 128B apart.
__global__ __launch_bounds__(512, 2) void rnn_rec(const float* __restrict__ Whh,
                                                  float* __restrict__ out,
                                                  int* __restrict__ flags,
                                                  unsigned short* __restrict__ ring){
  __shared__ unsigned short Ahi[2][16][520];   // [t-parity][batch][K] (+8 pad)
  __shared__ unsigned short Alo[2][16][520];

  const int bid = blockIdx.x;
  const int g  = bid & 3;
  const int i  = bid >> 2;
  const int tid = threadIdx.x;
  const int lane = tid & 63;
  const int w  = tid >> 6;
  const int ln = lane & 15;
  const int lq = lane >> 4;
  const int b0 = g * 16;
  const int ncol0 = i*128 + w*16;

  // --- resident W_hh fragments, full K=512 for this wave's 16 cols ---
  short8 whi[16], wlo[16];
  #pragma unroll
  for(int kt=0;kt<16;kt++){
    short8 h8, l8;
    const int kb = kt*32 + lq*8;
    #pragma unroll
    for(int j=0;j<8;j++){
      const float wv = Whh[(size_t)(kb+j)*U_SZ + ncol0 + ln];
      const unsigned short hb = f2bf(wv);
      const unsigned short lb = f2bf(wv - bf2f(hb));
      h8[j] = (short)hb; l8[j] = (short)lb;
    }
    whi[kt]=h8; wlo[kt]=l8;
  }
  // zero h_{-1} (both parities; buf 1 is fully overwritten before use anyway)
  for(int idx=tid; idx<2*16*520; idx+=512){
    ((unsigned short*)Ahi)[idx]=0;
    ((unsigned short*)Alo)[idx]=0;
  }
  __syncthreads();

  float xwv[4], hprev[4];
  #pragma unroll
  for(int r=0;r<4;r++){
    xwv[r] = out[((size_t)(b0 + lq*4 + r)*T_SZ + 0)*U_SZ + ncol0 + ln];
    hprev[r] = 0.f;
  }

  const int selp = lane >> 5;          // chunk plane
  const int mrow = (lane & 31) >> 1;   // chunk row (batch)
  const int qh   = lane & 1;           // chunk 8-col half

  for(int t=0;t<T_SZ;t++){
    const int buf = t & 1;
    if(t>0){
      // delayed fp32 h-store for t-1 (fire-and-forget; drains during MFMA)
      #pragma unroll
      for(int r=0;r<4;r++)
        out[((size_t)(b0 + lq*4 + r)*T_SZ + (t-1))*U_SZ + ncol0 + ln] = hprev[r];
      { // spin: lanes 0..2 each own one peer's flag for chunk (p, w)
        const int p = lane + (lane >= i);
        bool done = (lane >= 3);
        while(__ballot(!done)){
          if(!done){
            const int f = __hip_atomic_load(&flags[((g*4+p)*8 + w)*32],
                                            __ATOMIC_RELAXED, __HIP_MEMORY_SCOPE_AGENT);
            done = (f >= t);
          }
        }
      }
      asm volatile("" ::: "memory");       // compiler ordering: poll -> ring reads
      const size_t slot = (size_t)((t-1)&1);
      #pragma unroll
      for(int s=0;s<3;s++){
        const int p = s + (s >= i);
        const unsigned long long* rb = (const unsigned long long*)ring
            + (((slot*4 + g)*4 + p)*8 + w)*128 + selp*64 + mrow*4 + qh*2;
        chunk16 cc;
        cc.q[0] = __hip_atomic_load(rb+0, __ATOMIC_RELAXED, __HIP_MEMORY_SCOPE_AGENT);
        cc.q[1] = __hip_atomic_load(rb+1, __ATOMIC_RELAXED, __HIP_MEMORY_SCOPE_AGENT);
        unsigned short* dst = selp ? &Alo[buf][mrow][p*128 + w*16 + qh*8]
                                   : &Ahi[buf][mrow][p*128 + w*16 + qh*8];
        *(short8*)dst = cc.v;
      }
    }
    __syncthreads();                        // B1: A[buf] (= h_{t-1}) complete

    f32x4 c_hh = {0.f,0.f,0.f,0.f}, c_hl = {0.f,0.f,0.f,0.f}, c_lh = {0.f,0.f,0.f,0.f};
    #pragma unroll
    for(int kt=0;kt<16;kt++){
      const int k = kt*32 + lq*8;
      const short8 ah = *(const short8*)&Ahi[buf][ln][k];
      const short8 al = *(const short8*)&Alo[buf][ln][k];
      c_hh = __builtin_amdgcn_mfma_f32_16x16x32_bf16(ah, whi[kt], c_hh, 0, 0, 0);
      c_hl = __builtin_amdgcn_mfma_f32_16x16x32_bf16(ah, wlo[kt], c_hl, 0, 0, 0);
      c_lh = __builtin_amdgcn_mfma_f32_16x16x32_bf16(al, whi[kt], c_lh, 0, 0, 0);
    }
    const f32x4 csum = c_hh + c_hl + c_lh;
    const int nbuf = buf ^ 1;
    #pragma unroll
    for(int r=0;r<4;r++){
      float pre = csum[r] + xwv[r];
      pre = fminf(fmaxf(pre, -12.f), 12.f);
      const float e = __expf(2.f*pre);
      const float h = (e-1.f)/(e+1.f);      // tanh
      hprev[r] = h;
      const unsigned short hb = f2bf(h);
      const unsigned short lb = f2bf(h - bf2f(hb));
      Ahi[nbuf][lq*4+r][ncol0+ln] = hb;     // own cols of A for step t+1
      Alo[nbuf][lq*4+r][ncol0+ln] = lb;
    }
    // publish own 16-col chunk: same-wave LDS readback (transpose) -> ring
    {
      const unsigned short* src = selp ? &Alo[nbuf][mrow][ncol0 + qh*8]
                                       : &Ahi[nbuf][mrow][ncol0 + qh*8];
      chunk16 ck; ck.v = *(const short8*)src;
      unsigned long long* rb = (unsigned long long*)ring
          + ((((size_t)(t&1)*4 + g)*4 + i)*8 + w)*128 + selp*64 + mrow*4 + qh*2;
      __hip_atomic_store(rb+0, ck.q[0], __ATOMIC_RELAXED, __HIP_MEMORY_SCOPE_AGENT);
      __hip_atomic_store(rb+1, ck.q[1], __ATOMIC_RELAXED, __HIP_MEMORY_SCOPE_AGENT);
    }
    asm volatile("s_waitcnt vmcnt(0)" ::: "memory");   // ring visible before flag
    if(lane==0)
      __hip_atomic_store(&flags[((g*4+i)*8 + w)*32], t+1,
                         __ATOMIC_RELAXED, __HIP_MEMORY_SCOPE_AGENT);
    // prefetch xw for t+1 (after flag: never drained on critical path)
    {
      const int tn = (t < T_SZ-1) ? t+1 : t;
      #pragma unroll
      for(int r=0;r<4;r++)
        xwv[r] = out[((size_t)(b0 + lq*4 + r)*T_SZ + tn)*U_SZ + ncol0 + ln];
    }
    // no second barrier: A double-buffer + B1(t+1) orders all cross-wave deps.
  }
  #pragma unroll
  for(int r=0;r<4;r++)
    out[((size_t)(b0 + lq*4 + r)*T_SZ + (T_SZ-1))*U_SZ + ncol0 + ln] = hprev[r];
}

extern "C" void kernel_launch(void* const* d_in, const int* in_sizes, int n_in,
                              void* d_out, int out_size, void* d_ws, size_t ws_size,
                              hipStream_t stream) {
  (void)in_sizes; (void)n_in; (void)out_size; (void)ws_size;
  const float* X   = (const float*)d_in[0];  // [64,1024,256]
  const float* Wxh = (const float*)d_in[1];  // [256,512]
  const float* Whh = (const float*)d_in[2];  // [512,512]
  const float* bh  = (const float*)d_in[3];  // [512]
  float* out = (float*)d_out;                // [64,1024,512]

  int* flags = (int*)d_ws;                                       // 128 flags x 128B (poison<0 OK)
  unsigned short* ring = (unsigned short*)((char*)d_ws + 16384); // 256 KB ring

  xw_gemm<<<dim3(512, 8), 256, 0, stream>>>(X, Wxh, bh, out);
  rnn_rec<<<16, 512, 0, stream>>>(Whh, out, flags, ring);
}